// Round 4
// baseline (172.541 us; speedup 1.0000x reference)
//
#include <hip/hip_runtime.h>

#define N_ROWS 8192
#define N_LBL  1024
#define KMAX   64

constexpr float C_COS_M  = (float)0.8775825618903728;   // cos(0.5)
constexpr float C_SIN_M  = (float)0.479425538604203;    // sin(0.5)
constexpr float C_THRESH = (float)-0.8775825618903728;  // cos(pi-0.5)
constexpr float C_MM     = (float)0.2397127693021015;   // sin(pi-0.5)*0.5
constexpr float C_ALPHA  = 0.1f;
constexpr float C_VALID  = 0.8f;
constexpr float C_K2E    = (float)(1.0 / (0.07 * 0.6931471805599453)); // 1/(T*ln2)
constexpr float C_LN2    = 0.6931471805599453f;

typedef short s16x8 __attribute__((ext_vector_type(8)));
typedef float f32x4 __attribute__((ext_vector_type(4)));

__device__ __forceinline__ unsigned f2bf(float f) {
    unsigned u = __float_as_uint(f);
    return (u + 0x7fffu + ((u >> 16) & 1u)) >> 16;   // RNE to bf16
}
__device__ __forceinline__ float bflo(unsigned u) { return __uint_as_float(u << 16); }
__device__ __forceinline__ float bfhi(unsigned u) { return __uint_as_float(u & 0xffff0000u); }

// async 16B global->LDS (lands at wave-uniform base + lane*16)
__device__ __forceinline__ void gl_lds16(const unsigned* g, void* lds) {
    __builtin_amdgcn_global_load_lds(
        (const __attribute__((address_space(1))) unsigned*)g,
        (__attribute__((address_space(3))) unsigned*)lds, 16, 0, 0);
}

// ---------------- K1: row-normalize -> packed bf16; zero gsum ----------------
__global__ void k_norm(const float* __restrict__ f1, const float* __restrict__ f2,
                       unsigned* __restrict__ f1n, unsigned* __restrict__ f2n,
                       float* __restrict__ gsum) {
    if (blockIdx.x == 0 && threadIdx.x == 0) { gsum[0] = 0.f; gsum[1] = 0.f; }
    int b = blockIdx.x * 4 + (threadIdx.x >> 6);
    int l = threadIdx.x & 63;
    int row = (b < N_ROWS) ? b : (b - N_ROWS);
    const float* src = (b < N_ROWS) ? f1 : f2;
    unsigned* dst = (b < N_ROWS) ? f1n : f2n;
    float2 v = ((const float2*)(src + row * 128))[l];
    float ss = v.x * v.x + v.y * v.y;
    #pragma unroll
    for (int k = 1; k < 64; k <<= 1) ss += __shfl_xor(ss, k);
    float inv = 1.0f / fmaxf(sqrtf(ss), 1e-12f);
    dst[row * 64 + l] = f2bf(v.x * inv) | (f2bf(v.y * inv) << 16);
}

// ---------------- K2: one block per label: gather members, all k^2 positive sims --------
__global__ __launch_bounds__(64) void k_pairs(const unsigned* __restrict__ f1n,
                                              const unsigned* __restrict__ f2n,
                                              const int* __restrict__ labels,
                                              float* __restrict__ simlist,
                                              float* __restrict__ rt,
                                              int* __restrict__ rowcnt,
                                              float* __restrict__ gsum,
                                              float* __restrict__ out) {
    __shared__ int members[KMAX];
    __shared__ unsigned ldsF1[KMAX * 64];
    __shared__ unsigned ldsF2[KMAX * 64];
    const int lab = blockIdx.x, lane = threadIdx.x;
    if (lab == 0 && lane == 0) out[0] = 0.f;

    // ballot-scan the 8192 labels for members of this label
    int base = 0;
    #pragma unroll 2
    for (int c = 0; c < 128; ++c) {
        int lv = labels[c * 64 + lane];
        unsigned long long m = __ballot(lv == lab);
        if (lv == lab) {
            int idx = base + __popcll(m & ((1ull << lane) - 1ull));
            if (idx < KMAX) members[idx] = c * 64 + lane;
        }
        base += (int)__popcll(m);
    }
    int k = base < KMAX ? base : KMAX;
    __syncthreads();
    if (k == 0) return;

    // load member rows to LDS (one uint per lane per row)
    for (int m = 0; m < k; ++m) {
        int r = members[m];
        ldsF1[m * 64 + lane] = f1n[r * 64 + lane];
        ldsF2[m * 64 + lane] = f2n[r * 64 + lane];
        if (lane == 0) rowcnt[r] = k;
    }
    __syncthreads();

    const int g = lane >> 4, sl = lane & 15;
    float bsim = 0.f;
    for (int mi = 0; mi < k; ++mi) {
        const int ri = members[mi];
        uint4 a = ((const uint4*)(ldsF1 + mi * 64))[sl];
        float a0 = bflo(a.x), a1 = bfhi(a.x), a2 = bflo(a.y), a3 = bfhi(a.y);
        float a4 = bflo(a.z), a5 = bfhi(a.z), a6 = bflo(a.w), a7 = bfhi(a.w);
        float accfp = 0.f;
        for (int mj = g; mj < k; mj += 4) {
            uint4 bb = ((const uint4*)(ldsF2 + mj * 64))[sl];
            float p = a0 * bflo(bb.x) + a1 * bfhi(bb.x) + a2 * bflo(bb.y) + a3 * bfhi(bb.y)
                    + a4 * bflo(bb.z) + a5 * bfhi(bb.z) + a6 * bflo(bb.w) + a7 * bfhi(bb.w);
            p += __shfl_xor(p, 1);
            p += __shfl_xor(p, 2);
            p += __shfl_xor(p, 4);
            p += __shfl_xor(p, 8);
            float s = fminf(1.f, fmaxf(-1.f, p));
            float ctm = s * C_COS_M - sqrtf(fmaxf(0.f, 1.f - s * s)) * C_SIN_M;
            float fpv = (s > C_THRESH) ? ctm : (s - C_MM);
            if (sl == 0) simlist[ri * 64 + mj] = s;
            accfp += fpv;
            bsim += s;   // replicated over 16 lanes of group; fixed in final reduce
        }
        accfp += __shfl_xor(accfp, 16);
        accfp += __shfl_xor(accfp, 32);
        if (lane == 0) rt[ri] = accfp / (float)k;
    }
    bsim += __shfl_xor(bsim, 16);
    bsim += __shfl_xor(bsim, 32);
    if (lane == 0) {
        atomicAdd(&gsum[0], bsim);
        atomicAdd(&gsum[1], (float)(k * k));
    }
}

// ---------------- K3: dense pass — every entry treated as negative ----------------
template <bool WV>
__device__ __forceinline__ void epi_accum(const f32x4 (&acc)[4][2], const float (&rtv)[4][4],
                                          float (&lnp)[4][4], float tval) {
    #pragma unroll
    for (int mt = 0; mt < 4; ++mt)
        #pragma unroll
        for (int nt = 0; nt < 2; ++nt)
            #pragma unroll
            for (int r = 0; r < 4; ++r) {
                float s = acc[mt][nt][r];          // |s| < 1 always: clamp non-binding
                float u = C_K2E * s;
                float m = tval + s;
                float arg = (s > rtv[mt][r]) ? u * m : u;
                float e = __builtin_amdgcn_exp2f(arg);
                if (WV) { float cz = fmaxf(s, 0.f); e *= cz * cz + 1.f; }
                lnp[mt][r] += e;
            }
}

__global__ __launch_bounds__(512, 4) void k_passB(const unsigned* __restrict__ f1n,
                                                  const unsigned* __restrict__ f2n,
                                                  const float* __restrict__ rt,
                                                  const float* __restrict__ gsum,
                                                  float* __restrict__ lnacc2) {
    __shared__ __align__(16) unsigned char ldsA[32768];
    __shared__ __align__(16) unsigned char ldsB[32768];
    const int tid = threadIdx.x;
    const int wave = tid >> 6, lane = tid & 63;
    const int wr = wave >> 2, wc = wave & 3;        // 2 x 4 wave grid; wave tile 64x32
    const int quad = lane >> 4, l15 = lane & 15;
    const int rowbase = blockIdx.x * 128;
    const float tval = C_ALPHA * gsum[0] / gsum[1];
    const bool wv = (tval > C_VALID);

    // staging geometry (512 threads, 32KB per buffer, 4 iterations of 16B/lane):
    // slot index s = it*512 + tid; row = s>>4, q = s&15. LDS slot (row,q) receives
    // global chunk (row, q ^ (row&15)); (row&15) == (tid>>4)&15, constant over it.
    const int srow = tid >> 4;                        // 0..31
    const int sq   = (tid & 15) ^ (srow & 15);
    const int goff = srow * 64 + sq * 4;              // uint offset; += 2048/it
    const int loff = wave * 1024;                     // LDS byte base; += 8192/it

    {   // stage A (once) + B ctile 0, async
        const unsigned* gA = f1n + rowbase * 64 + goff;
        const unsigned* gB = f2n + (blockIdx.y * 1024) * 64 + goff;
        #pragma unroll
        for (int it = 0; it < 4; ++it) {
            gl_lds16(gA + it * 2048, ldsA + loff + it * 8192);
            gl_lds16(gB + it * 2048, ldsB + loff + it * 8192);
        }
    }

    float rtv[4][4];
    #pragma unroll
    for (int mt = 0; mt < 4; ++mt)
        #pragma unroll
        for (int r = 0; r < 4; ++r)
            rtv[mt][r] = rt[rowbase + wr * 64 + mt * 16 + quad * 4 + r];

    __syncthreads();   // A and B0 resident

    float lnp[4][4] = {};
    #pragma unroll 1
    for (int ctile = 0; ctile < 8; ++ctile) {
        f32x4 zero = {0.f, 0.f, 0.f, 0.f};
        f32x4 acc[4][2];
        #pragma unroll
        for (int mt = 0; mt < 4; ++mt)
            #pragma unroll
            for (int nt = 0; nt < 2; ++nt) acc[mt][nt] = zero;

        #pragma unroll
        for (int ks = 0; ks < 4; ++ks) {
            s16x8 af[4], bfr[2];
            #pragma unroll
            for (int mt = 0; mt < 4; ++mt) {
                int row = wr * 64 + mt * 16 + l15, q = ks * 4 + quad;
                af[mt] = *((const s16x8*)(ldsA + row * 256 + ((q ^ (row & 15)) << 4)));
            }
            #pragma unroll
            for (int nt = 0; nt < 2; ++nt) {
                int row = wc * 32 + nt * 16 + l15, q = ks * 4 + quad;
                bfr[nt] = *((const s16x8*)(ldsB + row * 256 + ((q ^ (row & 15)) << 4)));
            }
            #pragma unroll
            for (int mt = 0; mt < 4; ++mt)
                #pragma unroll
                for (int nt = 0; nt < 2; ++nt)
                    acc[mt][nt] = __builtin_amdgcn_mfma_f32_16x16x32_bf16(af[mt], bfr[nt],
                                                                          acc[mt][nt], 0, 0, 0);
        }

        __syncthreads();   // all waves finished reading B(ctile)
        if (ctile < 7) {   // async-stage B(ctile+1); latency hides under epilogue
            const unsigned* gB = f2n + (blockIdx.y * 1024 + (ctile + 1) * 128) * 64 + goff;
            #pragma unroll
            for (int it = 0; it < 4; ++it)
                gl_lds16(gB + it * 2048, ldsB + loff + it * 8192);
        }

        if (wv) epi_accum<true>(acc, rtv, lnp, tval);
        else    epi_accum<false>(acc, rtv, lnp, tval);

        if (ctile < 7) __syncthreads();   // vmcnt drained -> B(ctile+1) visible
    }

    // per-row partial sums: non-atomic slice store (32 slices, fully overwritten)
    const int slice = blockIdx.y * 4 + wc;
    #pragma unroll
    for (int mt = 0; mt < 4; ++mt)
        #pragma unroll
        for (int r = 0; r < 4; ++r) {
            float v = lnp[mt][r];
            v += __shfl_xor(v, 1);
            v += __shfl_xor(v, 2);
            v += __shfl_xor(v, 4);
            v += __shfl_xor(v, 8);
            if (l15 == 0)
                lnacc2[slice * N_ROWS + rowbase + wr * 64 + mt * 16 + quad * 4 + r] = v;
        }
}

// ---------------- K4: positive correction + per-row loss + fused final reduce ------------
__global__ void k_lossC(const float* __restrict__ simlist, const int* __restrict__ rowcnt,
                        const float* __restrict__ rt, const float* __restrict__ gsum,
                        const float* __restrict__ lnacc2, float* __restrict__ out) {
    int t = threadIdx.x;
    int sub = t >> 3, sl = t & 7;
    int i = blockIdx.x * 32 + sub;
    int cnt = rowcnt[i];
    if (cnt > KMAX) cnt = KMAX;
    float tval = C_ALPHA * gsum[0] / gsum[1];
    bool wv = (tval > C_VALID);
    float rti = rt[i];
    float lp = 0.f, den = 0.f;
    for (int e = sl; e < cnt; e += 8) {
        float s = simlist[i * 64 + e];
        // what k_passB added for this (pos) entry:
        float sh = (s > rti) ? s * (tval + s) : s;
        float en = __builtin_amdgcn_exp2f(C_K2E * sh);
        // true positive contribution:
        float ctm = s * C_COS_M - sqrtf(fmaxf(0.f, 1.f - s * s)) * C_SIN_M;
        float fp = (s > C_THRESH) ? ctm : (s - C_MM);
        float ep = __builtin_amdgcn_exp2f(C_K2E * fp);
        if (wv) {
            float cz = fmaxf(s, 0.f);
            en *= cz * cz + 1.f;
            float d = 1.f - s;
            ep *= d * d + 1.f;
        }
        den -= en;
        lp += ep;
    }
    // dense-pass partials: 32 slices, 4 per lane
    float lnsum = 0.f;
    #pragma unroll
    for (int p = 0; p < 4; ++p) lnsum += lnacc2[(sl + p * 8) * N_ROWS + i];
    #pragma unroll
    for (int k = 1; k < 8; k <<= 1) {
        den += __shfl_xor(den, k);
        lp += __shfl_xor(lp, k);
        lnsum += __shfl_xor(lnsum, k);
    }
    float ln = lnsum + den;
    float rl = (__builtin_amdgcn_logf(lp + ln) - __builtin_amdgcn_logf(lp)) * C_LN2;
    // all 8 sub-lanes hold rl; sum the wave's 8 rows (each counted once)
    rl += __shfl_xor(rl, 8);
    rl += __shfl_xor(rl, 16);
    rl += __shfl_xor(rl, 32);
    __shared__ float sa[4];
    if ((t & 63) == 0) sa[t >> 6] = rl;
    __syncthreads();
    if (t == 0)
        atomicAdd(out, (sa[0] + sa[1] + sa[2] + sa[3]) * (1.0f / (float)N_ROWS));
}

extern "C" void kernel_launch(void* const* d_in, const int* in_sizes, int n_in,
                              void* d_out, int out_size, void* d_ws, size_t ws_size,
                              hipStream_t stream) {
    (void)in_sizes; (void)n_in; (void)out_size; (void)ws_size;
    const float* f1 = (const float*)d_in[0];
    const float* f2 = (const float*)d_in[1];
    const int* labels = (const int*)d_in[2];
    float* out = (float*)d_out;
    char* ws = (char*)d_ws;

    // ws layout (bytes); everything is fully written by kernels before use -> no memsets
    unsigned* f1n   = (unsigned*)(ws + 0);              // 2 MB  bf16-packed
    unsigned* f2n   = (unsigned*)(ws + 2097152);        // 2 MB
    float* simlist  = (float*)(ws + 4194304);           // 2 MB (64 sims/row cap)
    float* rt       = (float*)(ws + 6291456);           // 32 KB
    int* rowcnt     = (int*)(ws + 6324224);             // 32 KB
    float* lnacc2   = (float*)(ws + 6356992);           // 1 MB  (32 slices x 8192)
    float* gsum     = (float*)(ws + 7405568);           // 8 B   (sum sim_pos, sum k^2)

    k_norm<<<dim3(4096), dim3(256), 0, stream>>>(f1, f2, f1n, f2n, gsum);
    k_pairs<<<dim3(N_LBL), dim3(64), 0, stream>>>(f1n, f2n, labels, simlist, rt, rowcnt,
                                                  gsum, out);
    k_passB<<<dim3(64, 8), dim3(512), 0, stream>>>(f1n, f2n, rt, gsum, lnacc2);
    k_lossC<<<dim3(256), dim3(256), 0, stream>>>(simlist, rowcnt, rt, gsum, lnacc2, out);
}

// Round 5
// 127.266 us; speedup vs baseline: 1.3558x; 1.3558x over previous
//
#include <hip/hip_runtime.h>

#define N_ROWS 8192
#define N_LBL  1024
#define KMAX   64

constexpr float C_COS_M  = (float)0.8775825618903728;   // cos(0.5)
constexpr float C_SIN_M  = (float)0.479425538604203;    // sin(0.5)
constexpr float C_THRESH = (float)-0.8775825618903728;  // cos(pi-0.5)
constexpr float C_MM     = (float)0.2397127693021015;   // sin(pi-0.5)*0.5
constexpr float C_ALPHA  = 0.1f;
constexpr float C_VALID  = 0.8f;
constexpr float C_K2E    = (float)(1.0 / (0.07 * 0.6931471805599453)); // 1/(T*ln2)
constexpr float C_LN2    = 0.6931471805599453f;

typedef short s16x8 __attribute__((ext_vector_type(8)));
typedef float f32x4 __attribute__((ext_vector_type(4)));

__device__ __forceinline__ unsigned f2bf(float f) {
    unsigned u = __float_as_uint(f);
    return (u + 0x7fffu + ((u >> 16) & 1u)) >> 16;   // RNE to bf16
}
__device__ __forceinline__ float bflo(unsigned u) { return __uint_as_float(u << 16); }
__device__ __forceinline__ float bfhi(unsigned u) { return __uint_as_float(u & 0xffff0000u); }

// async 16B global->LDS (lands at wave-uniform base + lane*16)
__device__ __forceinline__ void gl_lds16(const unsigned* g, void* lds) {
    __builtin_amdgcn_global_load_lds(
        (const __attribute__((address_space(1))) unsigned*)g,
        (__attribute__((address_space(3))) unsigned*)lds, 16, 0, 0);
}

// ---- K1: row-normalize -> packed bf16; scatter rows into fixed-stride label buckets ----
__global__ void k_norm(const float* __restrict__ f1, const float* __restrict__ f2,
                       const int* __restrict__ labels,
                       unsigned* __restrict__ f1n, unsigned* __restrict__ f2n,
                       int* __restrict__ hist, unsigned short* __restrict__ bucket,
                       float* __restrict__ out) {
    if (blockIdx.x == 0 && threadIdx.x == 0) out[0] = 0.f;
    int b = blockIdx.x * 4 + (threadIdx.x >> 6);
    int l = threadIdx.x & 63;
    int row = (b < N_ROWS) ? b : (b - N_ROWS);
    const float* src = (b < N_ROWS) ? f1 : f2;
    unsigned* dst = (b < N_ROWS) ? f1n : f2n;
    float2 v = ((const float2*)(src + row * 128))[l];
    float ss = v.x * v.x + v.y * v.y;
    #pragma unroll
    for (int k = 1; k < 64; k <<= 1) ss += __shfl_xor(ss, k);
    float inv = 1.0f / fmaxf(sqrtf(ss), 1e-12f);
    dst[row * 64 + l] = f2bf(v.x * inv) | (f2bf(v.y * inv) << 16);
    if (b < N_ROWS && l == 0) {
        int lab = labels[row];
        int p = atomicAdd(&hist[lab], 1);           // hist pre-zeroed by 4KB memset
        if (p < KMAX) bucket[lab * KMAX + p] = (unsigned short)row;
    }
}

// ---- K2: positive pairs from buckets: sims, rt[i], row_sim, rowcnt (4-wide ILP) ----
__global__ __launch_bounds__(64) void k_passA(const unsigned* __restrict__ f1n,
                                              const unsigned* __restrict__ f2n,
                                              const int* __restrict__ labels,
                                              const int* __restrict__ hist,
                                              const unsigned short* __restrict__ bucket,
                                              float* __restrict__ rt,
                                              float* __restrict__ row_sim,
                                              int* __restrict__ rowcnt,
                                              float* __restrict__ simlist) {
    int i = blockIdx.x, lane = threadIdx.x;
    int g = lane >> 4, sl = lane & 15;
    uint4 a = ((const uint4*)(f1n + i * 64))[sl];
    float a0 = bflo(a.x), a1 = bfhi(a.x), a2 = bflo(a.y), a3 = bfhi(a.y);
    float a4 = bflo(a.z), a5 = bfhi(a.z), a6 = bflo(a.w), a7 = bfhi(a.w);
    int lab = labels[i];
    int cnt = hist[lab];
    int cntc = cnt < KMAX ? cnt : KMAX;
    float rs_sim = 0.f, rs_fp = 0.f;
    for (int e0 = 0; e0 < cntc; e0 += 4) {
        int e = e0 + g;
        bool val = e < cntc;
        int j = bucket[lab * KMAX + (val ? e : 0)];
        uint4 b = ((const uint4*)(f2n + j * 64))[sl];
        float p = a0 * bflo(b.x) + a1 * bfhi(b.x) + a2 * bflo(b.y) + a3 * bfhi(b.y)
                + a4 * bflo(b.z) + a5 * bfhi(b.z) + a6 * bflo(b.w) + a7 * bfhi(b.w);
        p += __shfl_xor(p, 1);
        p += __shfl_xor(p, 2);
        p += __shfl_xor(p, 4);
        p += __shfl_xor(p, 8);
        float s = fminf(1.f, fmaxf(-1.f, p));
        float ctm = s * C_COS_M - sqrtf(fmaxf(0.f, 1.f - s * s)) * C_SIN_M;
        float fpv = (s > C_THRESH) ? ctm : (s - C_MM);
        if (val) {
            rs_sim += s;
            rs_fp += fpv;
            if (sl == 0) simlist[i * KMAX + e] = s;
        }
    }
    rs_sim += __shfl_xor(rs_sim, 16); rs_sim += __shfl_xor(rs_sim, 32);
    rs_fp  += __shfl_xor(rs_fp, 16);  rs_fp  += __shfl_xor(rs_fp, 32);
    if (lane == 0) {
        rt[i] = rs_fp / (float)cnt;
        row_sim[i] = rs_sim;
        rowcnt[i] = cnt;
    }
}

// ---- K3: t (and implicitly weight_valid) ----
__global__ void k_finalize(const float* __restrict__ row_sim, const int* __restrict__ hist,
                           float* __restrict__ tw) {
    int t = threadIdx.x;
    float ssum = 0.f, scnt = 0.f;
    if (t < N_LBL) { float h = (float)hist[t]; scnt = h * h; }
    #pragma unroll
    for (int p = 0; p < 8; ++p) ssum += row_sim[p * 1024 + t];
    #pragma unroll
    for (int k = 1; k < 64; k <<= 1) {
        ssum += __shfl_xor(ssum, k);
        scnt += __shfl_xor(scnt, k);
    }
    __shared__ float sa[16], sb[16];
    if ((t & 63) == 0) { sa[t >> 6] = ssum; sb[t >> 6] = scnt; }
    __syncthreads();
    if (t == 0) {
        float s1 = 0.f, s2 = 0.f;
        #pragma unroll
        for (int w = 0; w < 16; ++w) { s1 += sa[w]; s2 += sb[w]; }
        tw[0] = C_ALPHA * s1 / s2;
    }
}

// ---- K4: dense pass — every entry treated as negative ----
template <bool WV>
__device__ __forceinline__ void epi_accum(const f32x4 (&acc)[4][2], const float (&rtv)[4][4],
                                          float (&lnp)[4][4], float tval) {
    #pragma unroll
    for (int mt = 0; mt < 4; ++mt)
        #pragma unroll
        for (int nt = 0; nt < 2; ++nt)
            #pragma unroll
            for (int r = 0; r < 4; ++r) {
                float s = acc[mt][nt][r];          // |s| < 1 always: clamp non-binding
                float u = C_K2E * s;
                float m = tval + s;
                float arg = (s > rtv[mt][r]) ? u * m : u;
                float e = __builtin_amdgcn_exp2f(arg);
                if (WV) { float cz = fmaxf(s, 0.f); e *= cz * cz + 1.f; }
                lnp[mt][r] += e;
            }
}

__global__ __launch_bounds__(512, 4) void k_passB(const unsigned* __restrict__ f1n,
                                                  const unsigned* __restrict__ f2n,
                                                  const float* __restrict__ rt,
                                                  const float* __restrict__ tw,
                                                  float* __restrict__ lnacc2) {
    __shared__ __align__(16) unsigned char ldsA[32768];
    __shared__ __align__(16) unsigned char ldsB[32768];
    const int tid = threadIdx.x;
    const int wave = tid >> 6, lane = tid & 63;
    const int wr = wave >> 2, wc = wave & 3;        // 2 x 4 wave grid; wave tile 64x32
    const int quad = lane >> 4, l15 = lane & 15;
    const int rowbase = blockIdx.x * 128;
    const float tval = tw[0];
    const bool wv = (tval > C_VALID);

    const int srow = tid >> 4;                        // 0..31
    const int sq   = (tid & 15) ^ (srow & 15);
    const int goff = srow * 64 + sq * 4;              // uint offset; += 2048/it
    const int loff = wave * 1024;                     // LDS byte base; += 8192/it

    {   // stage A (once) + B ctile 0, async
        const unsigned* gA = f1n + rowbase * 64 + goff;
        const unsigned* gB = f2n + (blockIdx.y * 1024) * 64 + goff;
        #pragma unroll
        for (int it = 0; it < 4; ++it) {
            gl_lds16(gA + it * 2048, ldsA + loff + it * 8192);
            gl_lds16(gB + it * 2048, ldsB + loff + it * 8192);
        }
    }

    float rtv[4][4];
    #pragma unroll
    for (int mt = 0; mt < 4; ++mt)
        #pragma unroll
        for (int r = 0; r < 4; ++r)
            rtv[mt][r] = rt[rowbase + wr * 64 + mt * 16 + quad * 4 + r];

    __syncthreads();   // A and B0 resident

    float lnp[4][4] = {};
    #pragma unroll 1
    for (int ctile = 0; ctile < 8; ++ctile) {
        f32x4 zero = {0.f, 0.f, 0.f, 0.f};
        f32x4 acc[4][2];
        #pragma unroll
        for (int mt = 0; mt < 4; ++mt)
            #pragma unroll
            for (int nt = 0; nt < 2; ++nt) acc[mt][nt] = zero;

        #pragma unroll
        for (int ks = 0; ks < 4; ++ks) {
            s16x8 af[4], bfr[2];
            #pragma unroll
            for (int mt = 0; mt < 4; ++mt) {
                int row = wr * 64 + mt * 16 + l15, q = ks * 4 + quad;
                af[mt] = *((const s16x8*)(ldsA + row * 256 + ((q ^ (row & 15)) << 4)));
            }
            #pragma unroll
            for (int nt = 0; nt < 2; ++nt) {
                int row = wc * 32 + nt * 16 + l15, q = ks * 4 + quad;
                bfr[nt] = *((const s16x8*)(ldsB + row * 256 + ((q ^ (row & 15)) << 4)));
            }
            #pragma unroll
            for (int mt = 0; mt < 4; ++mt)
                #pragma unroll
                for (int nt = 0; nt < 2; ++nt)
                    acc[mt][nt] = __builtin_amdgcn_mfma_f32_16x16x32_bf16(af[mt], bfr[nt],
                                                                          acc[mt][nt], 0, 0, 0);
        }

        __syncthreads();   // all waves finished reading B(ctile)
        if (ctile < 7) {   // async-stage B(ctile+1); latency hides under epilogue
            const unsigned* gB = f2n + (blockIdx.y * 1024 + (ctile + 1) * 128) * 64 + goff;
            #pragma unroll
            for (int it = 0; it < 4; ++it)
                gl_lds16(gB + it * 2048, ldsB + loff + it * 8192);
        }

        if (wv) epi_accum<true>(acc, rtv, lnp, tval);
        else    epi_accum<false>(acc, rtv, lnp, tval);

        if (ctile < 7) __syncthreads();   // vmcnt drained -> B(ctile+1) visible
    }

    // per-row partial sums: non-atomic slice store (32 slices, fully overwritten)
    const int slice = blockIdx.y * 4 + wc;
    #pragma unroll
    for (int mt = 0; mt < 4; ++mt)
        #pragma unroll
        for (int r = 0; r < 4; ++r) {
            float v = lnp[mt][r];
            v += __shfl_xor(v, 1);
            v += __shfl_xor(v, 2);
            v += __shfl_xor(v, 4);
            v += __shfl_xor(v, 8);
            if (l15 == 0)
                lnacc2[slice * N_ROWS + rowbase + wr * 64 + mt * 16 + quad * 4 + r] = v;
        }
}

// ---- K5: positive correction + per-row loss + fused final reduce ----
__global__ void k_lossC(const float* __restrict__ simlist, const int* __restrict__ rowcnt,
                        const float* __restrict__ rt, const float* __restrict__ tw,
                        const float* __restrict__ lnacc2, float* __restrict__ out) {
    int t = threadIdx.x;
    int sub = t >> 3, sl = t & 7;
    int i = blockIdx.x * 32 + sub;
    int cnt = rowcnt[i];
    if (cnt > KMAX) cnt = KMAX;
    float tval = tw[0];
    bool wv = (tval > C_VALID);
    float rti = rt[i];
    float lp = 0.f, den = 0.f;
    for (int e = sl; e < cnt; e += 8) {
        float s = simlist[i * KMAX + e];
        // what k_passB added for this (pos) entry:
        float sh = (s > rti) ? s * (tval + s) : s;
        float en = __builtin_amdgcn_exp2f(C_K2E * sh);
        // true positive contribution:
        float ctm = s * C_COS_M - sqrtf(fmaxf(0.f, 1.f - s * s)) * C_SIN_M;
        float fp = (s > C_THRESH) ? ctm : (s - C_MM);
        float ep = __builtin_amdgcn_exp2f(C_K2E * fp);
        if (wv) {
            float cz = fmaxf(s, 0.f);
            en *= cz * cz + 1.f;
            float d = 1.f - s;
            ep *= d * d + 1.f;
        }
        den -= en;
        lp += ep;
    }
    // dense-pass partials: 32 slices, 4 per lane
    float lnsum = 0.f;
    #pragma unroll
    for (int p = 0; p < 4; ++p) lnsum += lnacc2[(sl + p * 8) * N_ROWS + i];
    #pragma unroll
    for (int k = 1; k < 8; k <<= 1) {
        den += __shfl_xor(den, k);
        lp += __shfl_xor(lp, k);
        lnsum += __shfl_xor(lnsum, k);
    }
    float ln = lnsum + den;
    float rl = (__builtin_amdgcn_logf(lp + ln) - __builtin_amdgcn_logf(lp)) * C_LN2;
    // all 8 sub-lanes hold rl; sum the wave's 8 rows (each counted once)
    rl += __shfl_xor(rl, 8);
    rl += __shfl_xor(rl, 16);
    rl += __shfl_xor(rl, 32);
    __shared__ float sa[4];
    if ((t & 63) == 0) sa[t >> 6] = rl;
    __syncthreads();
    if (t == 0)
        atomicAdd(out, (sa[0] + sa[1] + sa[2] + sa[3]) * (1.0f / (float)N_ROWS));
}

extern "C" void kernel_launch(void* const* d_in, const int* in_sizes, int n_in,
                              void* d_out, int out_size, void* d_ws, size_t ws_size,
                              hipStream_t stream) {
    (void)in_sizes; (void)n_in; (void)out_size; (void)ws_size;
    const float* f1 = (const float*)d_in[0];
    const float* f2 = (const float*)d_in[1];
    const int* labels = (const int*)d_in[2];
    float* out = (float*)d_out;
    char* ws = (char*)d_ws;

    // ws layout (bytes); only hist needs pre-zero (atomic counters)
    unsigned* f1n          = (unsigned*)(ws + 0);              // 2 MB  bf16-packed
    unsigned* f2n          = (unsigned*)(ws + 2097152);        // 2 MB
    float* simlist         = (float*)(ws + 4194304);           // 2 MB (64 sims/row cap)
    float* rt              = (float*)(ws + 6291456);           // 32 KB
    float* row_sim         = (float*)(ws + 6324224);           // 32 KB
    int* rowcnt            = (int*)(ws + 6356992);             // 32 KB
    float* lnacc2          = (float*)(ws + 6389760);           // 1 MB  (32 slices x 8192)
    unsigned short* bucket = (unsigned short*)(ws + 7438336);  // 128 KB (1024 x 64 x u16)
    float* tw              = (float*)(ws + 7569408);           // 4 B
    int* hist              = (int*)(ws + 7569472);             // 4 KB  -- zeroed

    hipMemsetAsync(hist, 0, 4096, stream);

    k_norm<<<dim3(4096), dim3(256), 0, stream>>>(f1, f2, labels, f1n, f2n, hist, bucket, out);
    k_passA<<<dim3(N_ROWS), dim3(64), 0, stream>>>(f1n, f2n, labels, hist, bucket,
                                                   rt, row_sim, rowcnt, simlist);
    k_finalize<<<dim3(1), dim3(1024), 0, stream>>>(row_sim, hist, tw);
    k_passB<<<dim3(64, 8), dim3(512), 0, stream>>>(f1n, f2n, rt, tw, lnacc2);
    k_lossC<<<dim3(256), dim3(256), 0, stream>>>(simlist, rowcnt, rt, tw, lnacc2, out);
}

// Round 6
// 117.875 us; speedup vs baseline: 1.4638x; 1.0797x over previous
//
#include <hip/hip_runtime.h>

#define N_ROWS 8192
#define N_LBL  1024
#define KMAX   64

constexpr float C_COS_M  = (float)0.8775825618903728;   // cos(0.5)
constexpr float C_SIN_M  = (float)0.479425538604203;    // sin(0.5)
constexpr float C_THRESH = (float)-0.8775825618903728;  // cos(pi-0.5)
constexpr float C_MM     = (float)0.2397127693021015;   // sin(pi-0.5)*0.5
constexpr float C_ALPHA  = 0.1f;
constexpr float C_VALID  = 0.8f;
constexpr float C_K2E    = (float)(1.0 / (0.07 * 0.6931471805599453)); // 1/(T*ln2)
constexpr float C_LN2    = 0.6931471805599453f;

typedef short s16x8 __attribute__((ext_vector_type(8)));
typedef float f32x4 __attribute__((ext_vector_type(4)));

__device__ __forceinline__ unsigned f2bf(float f) {
    unsigned u = __float_as_uint(f);
    return (u + 0x7fffu + ((u >> 16) & 1u)) >> 16;   // RNE to bf16
}
__device__ __forceinline__ float bflo(unsigned u) { return __uint_as_float(u << 16); }
__device__ __forceinline__ float bfhi(unsigned u) { return __uint_as_float(u & 0xffff0000u); }

// async 16B global->LDS (lands at wave-uniform base + lane*16)
__device__ __forceinline__ void gl_lds16(const unsigned* g, void* lds) {
    __builtin_amdgcn_global_load_lds(
        (const __attribute__((address_space(1))) unsigned*)g,
        (__attribute__((address_space(3))) unsigned*)lds, 16, 0, 0);
}

// ---- K1: row-normalize -> packed bf16; scatter rows into fixed-stride label buckets ----
__global__ void k_norm(const float* __restrict__ f1, const float* __restrict__ f2,
                       const int* __restrict__ labels,
                       unsigned* __restrict__ f1n, unsigned* __restrict__ f2n,
                       int* __restrict__ hist, unsigned short* __restrict__ bucket,
                       float* __restrict__ out) {
    if (blockIdx.x == 0 && threadIdx.x == 0) out[0] = 0.f;
    int b = blockIdx.x * 4 + (threadIdx.x >> 6);
    int l = threadIdx.x & 63;
    int row = (b < N_ROWS) ? b : (b - N_ROWS);
    const float* src = (b < N_ROWS) ? f1 : f2;
    unsigned* dst = (b < N_ROWS) ? f1n : f2n;
    float2 v = ((const float2*)(src + row * 128))[l];
    float ss = v.x * v.x + v.y * v.y;
    #pragma unroll
    for (int k = 1; k < 64; k <<= 1) ss += __shfl_xor(ss, k);
    float inv = 1.0f / fmaxf(sqrtf(ss), 1e-12f);
    dst[row * 64 + l] = f2bf(v.x * inv) | (f2bf(v.y * inv) << 16);
    if (b < N_ROWS && l == 0) {
        int lab = labels[row];
        int p = atomicAdd(&hist[lab], 1);           // hist pre-zeroed by 4KB memset
        if (p < KMAX) bucket[lab * KMAX + p] = (unsigned short)row;
    }
}

// ---- K2: positive pairs from buckets: sims, rt[i], row_sim, rowcnt (4-wide ILP) ----
__global__ __launch_bounds__(64) void k_passA(const unsigned* __restrict__ f1n,
                                              const unsigned* __restrict__ f2n,
                                              const int* __restrict__ labels,
                                              const int* __restrict__ hist,
                                              const unsigned short* __restrict__ bucket,
                                              float* __restrict__ rt,
                                              float* __restrict__ row_sim,
                                              int* __restrict__ rowcnt,
                                              float* __restrict__ simlist) {
    int i = blockIdx.x, lane = threadIdx.x;
    int g = lane >> 4, sl = lane & 15;
    uint4 a = ((const uint4*)(f1n + i * 64))[sl];
    float a0 = bflo(a.x), a1 = bfhi(a.x), a2 = bflo(a.y), a3 = bfhi(a.y);
    float a4 = bflo(a.z), a5 = bfhi(a.z), a6 = bflo(a.w), a7 = bfhi(a.w);
    int lab = labels[i];
    int cnt = hist[lab];
    int cntc = cnt < KMAX ? cnt : KMAX;
    float rs_sim = 0.f, rs_fp = 0.f;
    for (int e0 = 0; e0 < cntc; e0 += 4) {
        int e = e0 + g;
        bool val = e < cntc;
        int j = bucket[lab * KMAX + (val ? e : 0)];
        uint4 b = ((const uint4*)(f2n + j * 64))[sl];
        float p = a0 * bflo(b.x) + a1 * bfhi(b.x) + a2 * bflo(b.y) + a3 * bfhi(b.y)
                + a4 * bflo(b.z) + a5 * bfhi(b.z) + a6 * bflo(b.w) + a7 * bfhi(b.w);
        p += __shfl_xor(p, 1);
        p += __shfl_xor(p, 2);
        p += __shfl_xor(p, 4);
        p += __shfl_xor(p, 8);
        float s = fminf(1.f, fmaxf(-1.f, p));
        float ctm = s * C_COS_M - sqrtf(fmaxf(0.f, 1.f - s * s)) * C_SIN_M;
        float fpv = (s > C_THRESH) ? ctm : (s - C_MM);
        if (val) {
            rs_sim += s;
            rs_fp += fpv;
            if (sl == 0) simlist[i * KMAX + e] = s;
        }
    }
    rs_sim += __shfl_xor(rs_sim, 16); rs_sim += __shfl_xor(rs_sim, 32);
    rs_fp  += __shfl_xor(rs_fp, 16);  rs_fp  += __shfl_xor(rs_fp, 32);
    if (lane == 0) {
        rt[i] = rs_fp / (float)cnt;
        row_sim[i] = rs_sim;
        rowcnt[i] = cnt;
    }
}

// ---- K3: t (and implicitly weight_valid) ----
__global__ void k_finalize(const float* __restrict__ row_sim, const int* __restrict__ hist,
                           float* __restrict__ tw) {
    int t = threadIdx.x;
    float ssum = 0.f, scnt = 0.f;
    if (t < N_LBL) { float h = (float)hist[t]; scnt = h * h; }
    #pragma unroll
    for (int p = 0; p < 8; ++p) ssum += row_sim[p * 1024 + t];
    #pragma unroll
    for (int k = 1; k < 64; k <<= 1) {
        ssum += __shfl_xor(ssum, k);
        scnt += __shfl_xor(scnt, k);
    }
    __shared__ float sa[16], sb[16];
    if ((t & 63) == 0) { sa[t >> 6] = ssum; sb[t >> 6] = scnt; }
    __syncthreads();
    if (t == 0) {
        float s1 = 0.f, s2 = 0.f;
        #pragma unroll
        for (int w = 0; w < 16; ++w) { s1 += sa[w]; s2 += sb[w]; }
        tw[0] = C_ALPHA * s1 / s2;
    }
}

// ---- K4: dense pass, barrier-free K-loop: A frags in VGPR, B streamed global->VGPR ----
__global__ __launch_bounds__(256, 3) void k_passB(const unsigned* __restrict__ f1n,
                                                  const unsigned* __restrict__ f2n,
                                                  const float* __restrict__ rt,
                                                  const float* __restrict__ tw,
                                                  float* __restrict__ lnacc2) {
    __shared__ __align__(16) unsigned char ldsA[32768];
    const int tid = threadIdx.x;
    const int wave = tid >> 6, lane = tid & 63;
    const int wr = wave >> 1, wc = wave & 1;     // wave tile: 64 rows x 512 cols
    const int quad = lane >> 4, l15 = lane & 15;
    const int rowbase = blockIdx.x * 128;
    const float tval = tw[0];
    const bool wv = (tval > C_VALID);

    // stage A tile (128 rows, 32 KB) once, XOR-swizzled on the global-source side
    {
        const int srow = tid >> 4;                        // 0..15
        const int sq   = (tid & 15) ^ (srow & 15);
        const unsigned* gA = f1n + rowbase * 64 + srow * 64 + sq * 4;
        const int loff = wave * 1024;
        #pragma unroll
        for (int it = 0; it < 8; ++it)
            gl_lds16(gA + it * 1024, ldsA + loff + it * 4096);
    }

    float rtv[4][4];
    #pragma unroll
    for (int mt = 0; mt < 4; ++mt)
        #pragma unroll
        for (int r = 0; r < 4; ++r)
            rtv[mt][r] = rt[rowbase + wr * 64 + mt * 16 + quad * 4 + r];

    __syncthreads();   // the only barrier: A resident

    // A fragments for the whole K=128 into VGPRs (16 x ds_read_b128)
    s16x8 af[4][4];
    #pragma unroll
    for (int mt = 0; mt < 4; ++mt)
        #pragma unroll
        for (int ks = 0; ks < 4; ++ks) {
            int row = wr * 64 + mt * 16 + l15, q = ks * 4 + quad;
            af[mt][ks] = *((const s16x8*)(ldsA + row * 256 + ((q ^ (row & 15)) << 4)));
        }

    // B fragment base: col = y*1024 + wc*512 + ct*16 + l15; addr = col*64 + ks*16 + quad*4
    const unsigned* bb = f2n + (blockIdx.y * 1024 + wc * 512 + l15) * 64 + quad * 4;

    float lnp[4][4] = {};

    auto loadB = [&](s16x8* b, int ct) {
        const unsigned* p = bb + ct * 1024;
        #pragma unroll
        for (int ks = 0; ks < 4; ++ks)
            b[ks] = *((const s16x8*)(p + ks * 16));
    };
    auto tile = [&](const s16x8* b) {
        f32x4 acc[4];
        #pragma unroll
        for (int mt = 0; mt < 4; ++mt) acc[mt] = (f32x4){0.f, 0.f, 0.f, 0.f};
        #pragma unroll
        for (int ks = 0; ks < 4; ++ks)
            #pragma unroll
            for (int mt = 0; mt < 4; ++mt)
                acc[mt] = __builtin_amdgcn_mfma_f32_16x16x32_bf16(af[mt][ks], b[ks],
                                                                  acc[mt], 0, 0, 0);
        #pragma unroll
        for (int mt = 0; mt < 4; ++mt)
            #pragma unroll
            for (int r = 0; r < 4; ++r) {
                float s = acc[mt][r];              // |s| < 1: clamp non-binding
                float u = C_K2E * s;
                float m = tval + s;
                float arg = (s > rtv[mt][r]) ? u * m : u;
                float e = __builtin_amdgcn_exp2f(arg);
                if (wv) { float cz = fmaxf(s, 0.f); e = e * (cz * cz + 1.f); }
                lnp[mt][r] += e;
            }
    };

    s16x8 b0[4], b1[4];
    loadB(b0, 0);
    #pragma unroll 1
    for (int ct = 0; ct < 32; ct += 2) {
        loadB(b1, ct + 1);         // prefetch next tile before consuming b0
        tile(b0);
        if (ct + 2 < 32) loadB(b0, ct + 2);
        tile(b1);
    }

    // per-row partial sums: non-atomic slice store (16 slices, fully overwritten)
    const int slice = blockIdx.y * 2 + wc;
    #pragma unroll
    for (int mt = 0; mt < 4; ++mt)
        #pragma unroll
        for (int r = 0; r < 4; ++r) {
            float v = lnp[mt][r];
            v += __shfl_xor(v, 1);
            v += __shfl_xor(v, 2);
            v += __shfl_xor(v, 4);
            v += __shfl_xor(v, 8);
            if (l15 == 0)
                lnacc2[slice * N_ROWS + rowbase + wr * 64 + mt * 16 + quad * 4 + r] = v;
        }
}

// ---- K5: positive correction + per-row loss + fused final reduce ----
__global__ void k_lossC(const float* __restrict__ simlist, const int* __restrict__ rowcnt,
                        const float* __restrict__ rt, const float* __restrict__ tw,
                        const float* __restrict__ lnacc2, float* __restrict__ out) {
    int t = threadIdx.x;
    int sub = t >> 3, sl = t & 7;
    int i = blockIdx.x * 32 + sub;
    int cnt = rowcnt[i];
    if (cnt > KMAX) cnt = KMAX;
    float tval = tw[0];
    bool wv = (tval > C_VALID);
    float rti = rt[i];
    float lp = 0.f, den = 0.f;
    for (int e = sl; e < cnt; e += 8) {
        float s = simlist[i * KMAX + e];
        // what k_passB added for this (pos) entry:
        float sh = (s > rti) ? s * (tval + s) : s;
        float en = __builtin_amdgcn_exp2f(C_K2E * sh);
        // true positive contribution:
        float ctm = s * C_COS_M - sqrtf(fmaxf(0.f, 1.f - s * s)) * C_SIN_M;
        float fp = (s > C_THRESH) ? ctm : (s - C_MM);
        float ep = __builtin_amdgcn_exp2f(C_K2E * fp);
        if (wv) {
            float cz = fmaxf(s, 0.f);
            en *= cz * cz + 1.f;
            float d = 1.f - s;
            ep *= d * d + 1.f;
        }
        den -= en;
        lp += ep;
    }
    // dense-pass partials: 16 slices, 2 per lane
    float lnsum = 0.f;
    #pragma unroll
    for (int p = 0; p < 2; ++p) lnsum += lnacc2[(sl + p * 8) * N_ROWS + i];
    #pragma unroll
    for (int k = 1; k < 8; k <<= 1) {
        den += __shfl_xor(den, k);
        lp += __shfl_xor(lp, k);
        lnsum += __shfl_xor(lnsum, k);
    }
    float ln = lnsum + den;
    float rl = (__builtin_amdgcn_logf(lp + ln) - __builtin_amdgcn_logf(lp)) * C_LN2;
    // all 8 sub-lanes hold rl; sum the wave's 8 rows (each counted once)
    rl += __shfl_xor(rl, 8);
    rl += __shfl_xor(rl, 16);
    rl += __shfl_xor(rl, 32);
    __shared__ float sa[4];
    if ((t & 63) == 0) sa[t >> 6] = rl;
    __syncthreads();
    if (t == 0)
        atomicAdd(out, (sa[0] + sa[1] + sa[2] + sa[3]) * (1.0f / (float)N_ROWS));
}

extern "C" void kernel_launch(void* const* d_in, const int* in_sizes, int n_in,
                              void* d_out, int out_size, void* d_ws, size_t ws_size,
                              hipStream_t stream) {
    (void)in_sizes; (void)n_in; (void)out_size; (void)ws_size;
    const float* f1 = (const float*)d_in[0];
    const float* f2 = (const float*)d_in[1];
    const int* labels = (const int*)d_in[2];
    float* out = (float*)d_out;
    char* ws = (char*)d_ws;

    // ws layout (bytes); only hist needs pre-zero (atomic counters)
    unsigned* f1n          = (unsigned*)(ws + 0);              // 2 MB  bf16-packed
    unsigned* f2n          = (unsigned*)(ws + 2097152);        // 2 MB
    float* simlist         = (float*)(ws + 4194304);           // 2 MB (64 sims/row cap)
    float* rt              = (float*)(ws + 6291456);           // 32 KB
    float* row_sim         = (float*)(ws + 6324224);           // 32 KB
    int* rowcnt            = (int*)(ws + 6356992);             // 32 KB
    float* lnacc2          = (float*)(ws + 6389760);           // 512 KB (16 slices x 8192)
    unsigned short* bucket = (unsigned short*)(ws + 6914048);  // 128 KB (1024 x 64 x u16)
    float* tw              = (float*)(ws + 7045120);           // 4 B
    int* hist              = (int*)(ws + 7045184);             // 4 KB  -- zeroed

    hipMemsetAsync(hist, 0, 4096, stream);

    k_norm<<<dim3(4096), dim3(256), 0, stream>>>(f1, f2, labels, f1n, f2n, hist, bucket, out);
    k_passA<<<dim3(N_ROWS), dim3(64), 0, stream>>>(f1n, f2n, labels, hist, bucket,
                                                   rt, row_sim, rowcnt, simlist);
    k_finalize<<<dim3(1), dim3(1024), 0, stream>>>(row_sim, hist, tw);
    k_passB<<<dim3(64, 8), dim3(256), 0, stream>>>(f1n, f2n, rt, tw, lnacc2);
    k_lossC<<<dim3(256), dim3(256), 0, stream>>>(simlist, rowcnt, rt, tw, lnacc2, out);
}